// Round 10
// baseline (933.771 us; speedup 1.0000x reference)
//
#include <hip/hip_runtime.h>
#include <cfloat>
#include <cmath>

#define NROWS 65536
#define DIM 256
#define KCODES 1024

// ws layout (bytes)
#define WS_LOSS_OFF   0        // float
#define WS_HIST_OFF   1024     // int[1024]
#define WS_E2_OFF     8192     // float[1024]  (np-pairwise-exact sum of e^2)
#define WS_X2_OFF     16384    // float[65536] (np-pairwise-exact sum of x^2)

// d_out layout (floats): [loss][quantized 16777216][perplexity][idx 65536]
#define OUT_Q    1
#define OUT_PERP 16777217
#define OUT_IDX  16777218

// numpy pairwise_sum over 128 elements of fl(p_j*p_j): 8-accumulator unroll,
// combine ((r0+r1)+(r2+r3))+((r4+r5)+(r6+r7)). Must NOT contract mul+add.
__device__ __forceinline__ float np_pairwise_sq_128(const float* __restrict__ p) {
#pragma clang fp contract(off)
    float r0 = p[0] * p[0], r1 = p[1] * p[1], r2 = p[2] * p[2], r3 = p[3] * p[3];
    float r4 = p[4] * p[4], r5 = p[5] * p[5], r6 = p[6] * p[6], r7 = p[7] * p[7];
    for (int i = 8; i < 128; i += 8) {
        r0 += p[i + 0] * p[i + 0];
        r1 += p[i + 1] * p[i + 1];
        r2 += p[i + 2] * p[i + 2];
        r3 += p[i + 3] * p[i + 3];
        r4 += p[i + 4] * p[i + 4];
        r5 += p[i + 5] * p[i + 5];
        r6 += p[i + 6] * p[i + 6];
        r7 += p[i + 7] * p[i + 7];
    }
    return ((r0 + r1) + (r2 + r3)) + ((r4 + r5) + (r6 + r7));
}

// one thread per row: out[row] = np-pairwise sum over 256 of fl(a_j^2)
__global__ __launch_bounds__(256) void k_np_sq(const float* __restrict__ a,
                                               float* __restrict__ out, int nrows) {
#pragma clang fp contract(off)
    int row = blockIdx.x * 256 + threadIdx.x;
    if (row >= nrows) return;
    const float* p = a + (long)row * 256;
    float s = np_pairwise_sq_128(p) + np_pairwise_sq_128(p + 128);
    out[row] = s;
}

// 32 rows/block. Emulates np f32: D = fl(fl(X2+E2[c]) - seqfma_dot(2x, e)).
// argmin with first-index tie-break.
__global__ __launch_bounds__(256) void k_argmin(const float* __restrict__ x,
                                                const float* __restrict__ emb,
                                                const float* __restrict__ e2,
                                                const float* __restrict__ x2,
                                                float* __restrict__ fidx) {
    __shared__ float4 Xs[32 * 64];
    __shared__ float4 Es[32 * 64];
    const int t = threadIdx.x, tx = t & 15, ty = t >> 4;
    const int blk = blockIdx.x;
    const float4* x4 = (const float4*)x;
    const float4* e4 = (const float4*)emb;
    const long xbase4 = (long)blk * 32 * 64;

    // stage 2*x tile (exact scaling): 2048 float4, swizzled chunk = kc ^ ((row>>1)&15)
#pragma unroll
    for (int i = 0; i < 8; ++i) {
        int idx = i * 256 + t;
        int r = idx >> 6, kc = idx & 63;
        float4 v = x4[xbase4 + idx];
        v.x *= 2.f; v.y *= 2.f; v.z *= 2.f; v.w *= 2.f;
        Xs[r * 64 + (kc ^ ((r >> 1) & 15))] = v;
    }

    const int r0 = 2 * ty, r1 = r0 + 1;
    const float X2a = x2[blk * 32 + r0];
    const float X2b = x2[blk * 32 + r1];
    float best0 = FLT_MAX, best1 = FLT_MAX;
    int bi0 = 0, bi1 = 0;
    const float4* xr0 = &Xs[r0 * 64];
    const float4* xr1 = &Xs[r1 * 64];
    const float4* er0 = &Es[(2 * tx) * 64];
    const float4* er1 = &Es[(2 * tx + 1) * 64];

    for (int kt = 0; kt < 32; ++kt) {
        __syncthreads();
#pragma unroll
        for (int i = 0; i < 8; ++i) {
            int idx = i * 256 + t;
            int r = idx >> 6, kc = idx & 63;
            Es[r * 64 + (kc ^ ((r >> 1) & 15))] = e4[(kt * 32 + r) * 64 + kc];
        }
        __syncthreads();

        // sequential single-accumulator fma chains, j = 0..255 in order (sgemm emulation)
        float a00 = 0.f, a01 = 0.f, a10 = 0.f, a11 = 0.f;
#pragma unroll 8
        for (int kc = 0; kc < 64; ++kc) {
            float4 xa = xr0[kc ^ ty];   // true chunk kc of row r0 (2x)
            float4 xb = xr1[kc ^ ty];
            float4 ea = er0[kc ^ tx];   // true chunk kc of code c0
            float4 eb = er1[kc ^ tx];
            a00 = fmaf(xa.x, ea.x, a00); a00 = fmaf(xa.y, ea.y, a00);
            a00 = fmaf(xa.z, ea.z, a00); a00 = fmaf(xa.w, ea.w, a00);
            a01 = fmaf(xa.x, eb.x, a01); a01 = fmaf(xa.y, eb.y, a01);
            a01 = fmaf(xa.z, eb.z, a01); a01 = fmaf(xa.w, eb.w, a01);
            a10 = fmaf(xb.x, ea.x, a10); a10 = fmaf(xb.y, ea.y, a10);
            a10 = fmaf(xb.z, ea.z, a10); a10 = fmaf(xb.w, ea.w, a10);
            a11 = fmaf(xb.x, eb.x, a11); a11 = fmaf(xb.y, eb.y, a11);
            a11 = fmaf(xb.z, eb.z, a11); a11 = fmaf(xb.w, eb.w, a11);
        }
        int c0 = kt * 32 + 2 * tx, c1 = c0 + 1;
        float e2a = e2[c0], e2b = e2[c1];
        // np rounding pipeline: S = fl(X2 + E2[c]); D = fl(S - M)
        float S00 = X2a + e2a, S01 = X2a + e2b;
        float S10 = X2b + e2a, S11 = X2b + e2b;
        float d00 = S00 - a00, d01 = S01 - a01;
        float d10 = S10 - a10, d11 = S11 - a11;
        // ascending c scan; strict < keeps first index
        if (d00 < best0) { best0 = d00; bi0 = c0; }
        if (d01 < best0) { best0 = d01; bi0 = c1; }
        if (d10 < best1) { best1 = d10; bi1 = c0; }
        if (d11 < best1) { best1 = d11; bi1 = c1; }
    }

    // merge across 16 tx lanes with first-index tie-break (ulp ties are common)
#pragma unroll
    for (int m = 1; m <= 8; m <<= 1) {
        float ob = __shfl_xor(best0, m); int oi = __shfl_xor(bi0, m);
        if (ob < best0 || (ob == best0 && oi < bi0)) { best0 = ob; bi0 = oi; }
        ob = __shfl_xor(best1, m); oi = __shfl_xor(bi1, m);
        if (ob < best1 || (ob == best1 && oi < bi1)) { best1 = ob; bi1 = oi; }
    }
    if (tx == 0) {
        int row = blk * 32 + r0;
        fidx[row] = (float)bi0;
        fidx[row + 1] = (float)bi1;
    }
}

// gather + straight-through + loss partials + histogram
__global__ __launch_bounds__(256) void k_quant(const float* __restrict__ x,
                                               const float* __restrict__ emb,
                                               const float* __restrict__ fidx,
                                               float* __restrict__ outq,
                                               float* __restrict__ loss_accum,
                                               int* __restrict__ hist) {
    const int t = threadIdx.x, w = t >> 6, l = t & 63;
    const int b = blockIdx.x;
    float lsum = 0.f;
    __shared__ float wsum[4];
    for (int it = 0; it < 16; ++it) {
        int row = b * 64 + it * 4 + w;
        int qi = (int)fidx[row];
        const float* xr = x + (long)row * 256;
        const float* er = emb + (long)qi * 256;
        float* orow = outq + (long)row * 256;
        if (l == 0) atomicAdd(&hist[qi], 1);
#pragma unroll
        for (int j = 0; j < 4; ++j) {
            float xv = xr[l + 64 * j];
            float ev = er[l + 64 * j];
            float diff = ev - xv;            // quantized - inputs (ref order)
            lsum += diff * diff;
            orow[l + 64 * j] = xv + diff;    // straight-through
        }
    }
    for (int m = 32; m; m >>= 1) lsum += __shfl_xor(lsum, m);
    if (l == 0) wsum[w] = lsum;
    __syncthreads();
    if (t == 0) atomicAdd(loss_accum, wsum[0] + wsum[1] + wsum[2] + wsum[3]);
}

__global__ __launch_bounds__(256) void k_final(const int* __restrict__ hist,
                                               const float* __restrict__ loss_accum,
                                               float* __restrict__ dout) {
    const int t = threadIdx.x;
    float s = 0.f;
#pragma unroll
    for (int i = 0; i < 4; ++i) {
        int cnt = hist[t * 4 + i];
        float p = (float)cnt * (1.0f / 65536.0f);
        s += p * logf(p + 1e-10f);
    }
    for (int m = 32; m; m >>= 1) s += __shfl_xor(s, m);
    __shared__ float ws2[4];
    if ((t & 63) == 0) ws2[t >> 6] = s;
    __syncthreads();
    if (t == 0) {
        float tot = ws2[0] + ws2[1] + ws2[2] + ws2[3];
        dout[0] = 1.25f * loss_accum[0] * (1.0f / 16777216.0f);
        dout[OUT_PERP] = expf(-tot);
    }
}

extern "C" void kernel_launch(void* const* d_in, const int* in_sizes, int n_in,
                              void* d_out, int out_size, void* d_ws, size_t ws_size,
                              hipStream_t stream) {
    const float* x = (const float*)d_in[0];
    const float* emb = (const float*)d_in[1];
    float* out = (float*)d_out;
    char* ws = (char*)d_ws;
    float* loss_accum = (float*)(ws + WS_LOSS_OFF);
    int* hist = (int*)(ws + WS_HIST_OFF);
    float* e2 = (float*)(ws + WS_E2_OFF);
    float* x2 = (float*)(ws + WS_X2_OFF);

    hipMemsetAsync(d_ws, 0, 5120, stream);  // zero loss accum + histogram
    k_np_sq<<<KCODES / 256, 256, 0, stream>>>(emb, e2, KCODES);
    k_np_sq<<<NROWS / 256, 256, 0, stream>>>(x, x2, NROWS);
    k_argmin<<<NROWS / 32, 256, 0, stream>>>(x, emb, e2, x2, out + OUT_IDX);
    k_quant<<<NROWS / 64, 256, 0, stream>>>(x, emb, out + OUT_IDX, out + OUT_Q, loss_accum, hist);
    k_final<<<1, 256, 0, stream>>>(hist, loss_accum, out);
}

// Round 12
// 453.835 us; speedup vs baseline: 2.0575x; 2.0575x over previous
//
#include <hip/hip_runtime.h>
#include <cfloat>
#include <cmath>

#define NROWS 65536
#define DIM 256
#define KCODES 1024
#define MARGIN 2e-4f

typedef __attribute__((ext_vector_type(8))) short bf16x8;
typedef __attribute__((ext_vector_type(4))) float f32x4;

// ws layout (bytes)
#define WS_LOSS_OFF   0        // float
#define WS_CNT_OFF    4        // int (global flagged count)
#define WS_HIST_OFF   1024     // int[1024]
#define WS_E2_OFF     8192     // float[1024]
#define WS_X2_OFF     16384    // float[65536]

// d_out layout (floats): [loss][quantized 16777216][perplexity][idx 65536]
#define OUT_Q    1
#define OUT_PERP 16777217
#define OUT_IDX  16777218
// scratch inside the quantized span (rewritten every launch, consumed before k_quant writes).
// Based at d_out+256 bytes to keep 16-byte alignment for bf16x8 loads.
#define SCR_FLAGLIST   0           // int[65536]  (row | cnt<<16)
#define SCR_FLAGCANDS  (1<<18)     // int[65536][8]
#define SCR_EH         (4<<20)     // ushort[1024*256]
#define SCR_EL         (5<<20)     // ushort[1024*256]

__device__ __forceinline__ unsigned short f2bf(float f) {   // RTNE
    unsigned u = __float_as_uint(f);
    return (unsigned short)((u + 0x7FFFu + ((u >> 16) & 1u)) >> 16);
}
__device__ __forceinline__ float bf2f(unsigned short h) {
    return __uint_as_float((unsigned)h << 16);
}

// ---- numpy pairwise sum of squares (validated bit-exact, round 10) ----
__device__ __forceinline__ float np_pairwise_sq_128(const float* __restrict__ p) {
#pragma clang fp contract(off)
    float r0 = p[0]*p[0], r1 = p[1]*p[1], r2 = p[2]*p[2], r3 = p[3]*p[3];
    float r4 = p[4]*p[4], r5 = p[5]*p[5], r6 = p[6]*p[6], r7 = p[7]*p[7];
    for (int i = 8; i < 128; i += 8) {
        r0 += p[i+0]*p[i+0]; r1 += p[i+1]*p[i+1]; r2 += p[i+2]*p[i+2]; r3 += p[i+3]*p[i+3];
        r4 += p[i+4]*p[i+4]; r5 += p[i+5]*p[i+5]; r6 += p[i+6]*p[i+6]; r7 += p[i+7]*p[i+7];
    }
    return ((r0+r1)+(r2+r3))+((r4+r5)+(r6+r7));
}
__global__ __launch_bounds__(256) void k_np_sq(const float* __restrict__ a,
                                               float* __restrict__ out, int nrows) {
#pragma clang fp contract(off)
    int row = blockIdx.x * 256 + threadIdx.x;
    if (row >= nrows) return;
    const float* p = a + (long)row * 256;
    out[row] = np_pairwise_sq_128(p) + np_pairwise_sq_128(p + 128);
}

// ---- split codebook into bf16 hi/lo ----
__global__ __launch_bounds__(256) void k_prep_e(const float* __restrict__ emb,
                                                unsigned short* __restrict__ eh,
                                                unsigned short* __restrict__ el) {
    int i = blockIdx.x * 256 + threadIdx.x;
    float v = emb[i];
    unsigned short h = f2bf(v);
    eh[i] = h;
    el[i] = f2bf(v - bf2f(h));
}

// ---- MFMA distance + per-row min + candidate collection ----
// block: 512 thr (8 waves), tile 32 rows x 1024 codes; wave: 32 rows x 128 codes
__global__ __launch_bounds__(512, 2) void k_mfma(
        const float* __restrict__ x,
        const unsigned short* __restrict__ eh, const unsigned short* __restrict__ el,
        const float* __restrict__ e2, const float* __restrict__ x2,
        float* __restrict__ fidx, int* __restrict__ gflagcnt,
        int* __restrict__ flaglist, int* __restrict__ flagcands) {
    __shared__ unsigned short xh_s[8192];   // 32 x 256 bf16 of fl(2x), XOR-swizzled
    __shared__ unsigned short xl_s[8192];
    __shared__ float e2_s[1024];
    __shared__ float x2_s[32];
    __shared__ float rowmin[8][32];
    __shared__ float finmin[32];
    __shared__ int   ccnt[32];
    __shared__ int   ccand[32][8];

    const int t = threadIdx.x;
    const int rb = blockIdx.x * 32;

    // stage A: 16 threads/row, 16 elems/thread; swizzle byte ^= (row&7)<<4
    {
        int row = t >> 4, seg = t & 15;
        const float4* p = (const float4*)(x + (long)(rb + row) * 256) + seg * 4;
        float4 v0 = p[0], v1 = p[1], v2 = p[2], v3 = p[3];
        float f[16] = {v0.x,v0.y,v0.z,v0.w, v1.x,v1.y,v1.z,v1.w,
                       v2.x,v2.y,v2.z,v2.w, v3.x,v3.y,v3.z,v3.w};
        unsigned short h[16], lo[16];
#pragma unroll
        for (int i = 0; i < 16; ++i) {
            float s = 2.0f * f[i];                 // exact
            h[i] = f2bf(s);
            lo[i] = f2bf(s - bf2f(h[i]));
        }
        int swz = (row & 7) << 4;
        int a0 = (row * 512 + seg * 32) ^ swz;
        int a1 = (row * 512 + seg * 32 + 16) ^ swz;
        uint4 H0, H1, L0, L1;
        H0.x = h[0]|(h[1]<<16);  H0.y = h[2]|(h[3]<<16);  H0.z = h[4]|(h[5]<<16);  H0.w = h[6]|(h[7]<<16);
        H1.x = h[8]|(h[9]<<16);  H1.y = h[10]|(h[11]<<16);H1.z = h[12]|(h[13]<<16);H1.w = h[14]|(h[15]<<16);
        L0.x = lo[0]|(lo[1]<<16);L0.y = lo[2]|(lo[3]<<16);L0.z = lo[4]|(lo[5]<<16);L0.w = lo[6]|(lo[7]<<16);
        L1.x = lo[8]|(lo[9]<<16);L1.y = lo[10]|(lo[11]<<16);L1.z = lo[12]|(lo[13]<<16);L1.w = lo[14]|(lo[15]<<16);
        *(uint4*)((char*)xh_s + a0) = H0;  *(uint4*)((char*)xh_s + a1) = H1;
        *(uint4*)((char*)xl_s + a0) = L0;  *(uint4*)((char*)xl_s + a1) = L1;
    }
    e2_s[t] = e2[t]; e2_s[512 + t] = e2[512 + t];
    if (t < 32) { x2_s[t] = x2[rb + t]; ccnt[t] = 0; }
    __syncthreads();

    const int w = t >> 6, l = t & 63, lo4 = l & 15, hi2 = l >> 4;
    const int wbase = w * 128;

    f32x4 acc[2][8];
#pragma unroll
    for (int rg = 0; rg < 2; ++rg)
#pragma unroll
        for (int n = 0; n < 8; ++n) acc[rg][n] = (f32x4){0.f, 0.f, 0.f, 0.f};

    for (int ks = 0; ks < 8; ++ks) {
        bf16x8 ah[2], al[2];
#pragma unroll
        for (int rg = 0; rg < 2; ++rg) {
            int row = rg * 16 + lo4;
            int byte = (row * 512 + ks * 64 + hi2 * 16) ^ ((row & 7) << 4);
            ah[rg] = *(const bf16x8*)((char*)xh_s + byte);
            al[rg] = *(const bf16x8*)((char*)xl_s + byte);
        }
        bf16x8 bh[8], bl[8];
#pragma unroll
        for (int n = 0; n < 8; ++n) {
            long off = (long)(wbase + n * 16 + lo4) * 256 + ks * 32 + hi2 * 8;
            bh[n] = *(const bf16x8*)(eh + off);
            bl[n] = *(const bf16x8*)(el + off);
        }
#pragma unroll
        for (int rg = 0; rg < 2; ++rg)
#pragma unroll
            for (int n = 0; n < 8; ++n) {
                acc[rg][n] = __builtin_amdgcn_mfma_f32_16x16x32_bf16(ah[rg], bh[n], acc[rg][n], 0, 0, 0);
                acc[rg][n] = __builtin_amdgcn_mfma_f32_16x16x32_bf16(ah[rg], bl[n], acc[rg][n], 0, 0, 0);
                acc[rg][n] = __builtin_amdgcn_mfma_f32_16x16x32_bf16(al[rg], bh[n], acc[rg][n], 0, 0, 0);
            }
    }

    // D = fl(fl(X2+E2) - M); per-row min; C layout: col=lane&15, row=(lane>>4)*4+reg
#pragma unroll
    for (int rg = 0; rg < 2; ++rg) {
        float m0 = FLT_MAX, m1 = FLT_MAX, m2 = FLT_MAX, m3 = FLT_MAX;
#pragma unroll
        for (int n = 0; n < 8; ++n) {
            int code = wbase + n * 16 + lo4;
            float E = e2_s[code];
#pragma unroll
            for (int j = 0; j < 4; ++j) {
                int row32 = rg * 16 + hi2 * 4 + j;
                float S = x2_s[row32] + E;
                float d = S - acc[rg][n][j];
                acc[rg][n][j] = d;
                if (j == 0) m0 = fminf(m0, d);
                if (j == 1) m1 = fminf(m1, d);
                if (j == 2) m2 = fminf(m2, d);
                if (j == 3) m3 = fminf(m3, d);
            }
        }
#pragma unroll
        for (int mm = 1; mm <= 8; mm <<= 1) {
            m0 = fminf(m0, __shfl_xor(m0, mm));
            m1 = fminf(m1, __shfl_xor(m1, mm));
            m2 = fminf(m2, __shfl_xor(m2, mm));
            m3 = fminf(m3, __shfl_xor(m3, mm));
        }
        if (lo4 == 0) {
            rowmin[w][rg * 16 + hi2 * 4 + 0] = m0;
            rowmin[w][rg * 16 + hi2 * 4 + 1] = m1;
            rowmin[w][rg * 16 + hi2 * 4 + 2] = m2;
            rowmin[w][rg * 16 + hi2 * 4 + 3] = m3;
        }
    }
    __syncthreads();
    if (t < 32) {
        float fm = rowmin[0][t];
#pragma unroll
        for (int ww = 1; ww < 8; ++ww) fm = fminf(fm, rowmin[ww][t]);
        finmin[t] = fm;
    }
    __syncthreads();

    // collect candidates within MARGIN of the row min
#pragma unroll
    for (int rg = 0; rg < 2; ++rg)
#pragma unroll
        for (int n = 0; n < 8; ++n)
#pragma unroll
            for (int j = 0; j < 4; ++j) {
                int row32 = rg * 16 + hi2 * 4 + j;
                int code = wbase + n * 16 + lo4;
                if (acc[rg][n][j] <= finmin[row32] + MARGIN) {
                    int slot = atomicAdd(&ccnt[row32], 1);
                    if (slot < 8) ccand[row32][slot] = code;
                }
            }
    __syncthreads();

    if (t < 32) {
        int row = rb + t, cnt = ccnt[t];
        if (cnt == 1) {
            fidx[row] = (float)ccand[t][0];
        } else {
            int s = atomicAdd(gflagcnt, 1);
            int cc = cnt > 8 ? 9 : cnt;
            flaglist[s] = row | (cc << 16);
#pragma unroll
            for (int k = 0; k < 8; ++k)
                flagcands[s * 8 + k] = (k < cnt && k < 8) ? ccand[t][k] : 0;
        }
    }
}

// ---- exact (validated-emulation) refine of flagged rows ----
__global__ __launch_bounds__(256) void k_refine(const float* __restrict__ x,
                                                const float* __restrict__ emb,
                                                const float* __restrict__ e2,
                                                const float* __restrict__ x2,
                                                const int* __restrict__ gflagcnt,
                                                const int* __restrict__ flaglist,
                                                const int* __restrict__ flagcands,
                                                float* __restrict__ fidx) {
    const int t = threadIdx.x, l = t & 63;
    const int gw = blockIdx.x * 4 + (t >> 6);
    const int total = *gflagcnt;
    for (int slot = gw; slot < total; slot += 1024) {
        int e = flaglist[slot];
        int row = e & 0xFFFF, cnt = e >> 16;
        const float* xr = x + (long)row * 256;
        float bd = FLT_MAX; int bc = 0x7FFFFFFF;
        if (cnt <= 8) {
            if (l < cnt) {
                int c = flagcands[slot * 8 + l];
                const float* er = emb + (long)c * 256;
                float m = 0.f;
                for (int j = 0; j < 256; ++j) m = fmaf(2.0f * xr[j], er[j], m);
                bd = (x2[row] + e2[c]) - m; bc = c;
            }
        } else {
            for (int ci = 0; ci < 16; ++ci) {
                int c = ci * 64 + l;
                const float* er = emb + (long)c * 256;
                float m = 0.f;
                for (int j = 0; j < 256; ++j) m = fmaf(2.0f * xr[j], er[j], m);
                float d = (x2[row] + e2[c]) - m;
                if (d < bd || (d == bd && c < bc)) { bd = d; bc = c; }
            }
        }
#pragma unroll
        for (int mm = 1; mm <= 32; mm <<= 1) {
            float od = __shfl_xor(bd, mm); int oc = __shfl_xor(bc, mm);
            if (od < bd || (od == bd && oc < bc)) { bd = od; bc = oc; }
        }
        if (l == 0) fidx[row] = (float)bc;
    }
}

// ---- gather + straight-through + loss + histogram (float4) ----
__global__ __launch_bounds__(256) void k_quant(const float* __restrict__ x,
                                               const float* __restrict__ emb,
                                               const float* __restrict__ fidx,
                                               float* __restrict__ outq,
                                               float* __restrict__ loss_accum,
                                               int* __restrict__ hist) {
    const int t = threadIdx.x, w = t >> 6, l = t & 63;
    const int b = blockIdx.x;
    float lsum = 0.f;
    __shared__ float wsum[4];
    for (int it = 0; it < 16; ++it) {
        int row = b * 64 + it * 4 + w;
        int qi = (int)fidx[row];
        if (l == 0) atomicAdd(&hist[qi], 1);
        float4 xv = ((const float4*)(x + (long)row * 256))[l];
        float4 ev = ((const float4*)(emb + (long)qi * 256))[l];
        float dx = ev.x - xv.x, dy = ev.y - xv.y, dz = ev.z - xv.z, dw = ev.w - xv.w;
        lsum += dx * dx + dy * dy + dz * dz + dw * dw;
        float4 o = {xv.x + dx, xv.y + dy, xv.z + dz, xv.w + dw};
        ((float4*)(outq + (long)row * 256))[l] = o;
    }
    for (int m = 32; m; m >>= 1) lsum += __shfl_xor(lsum, m);
    if (l == 0) wsum[w] = lsum;
    __syncthreads();
    if (t == 0) atomicAdd(loss_accum, wsum[0] + wsum[1] + wsum[2] + wsum[3]);
}

__global__ __launch_bounds__(256) void k_final(const int* __restrict__ hist,
                                               const float* __restrict__ loss_accum,
                                               float* __restrict__ dout) {
    const int t = threadIdx.x;
    float s = 0.f;
#pragma unroll
    for (int i = 0; i < 4; ++i) {
        int cnt = hist[t * 4 + i];
        float p = (float)cnt * (1.0f / 65536.0f);
        s += p * logf(p + 1e-10f);
    }
    for (int m = 32; m; m >>= 1) s += __shfl_xor(s, m);
    __shared__ float ws2[4];
    if ((t & 63) == 0) ws2[t >> 6] = s;
    __syncthreads();
    if (t == 0) {
        float tot = ws2[0] + ws2[1] + ws2[2] + ws2[3];
        dout[0] = 1.25f * loss_accum[0] * (1.0f / 16777216.0f);
        dout[OUT_PERP] = expf(-tot);
    }
}

extern "C" void kernel_launch(void* const* d_in, const int* in_sizes, int n_in,
                              void* d_out, int out_size, void* d_ws, size_t ws_size,
                              hipStream_t stream) {
    const float* x = (const float*)d_in[0];
    const float* emb = (const float*)d_in[1];
    float* out = (float*)d_out;
    char* ws = (char*)d_ws;
    float* loss_accum = (float*)(ws + WS_LOSS_OFF);
    int* gflagcnt = (int*)(ws + WS_CNT_OFF);
    int* hist = (int*)(ws + WS_HIST_OFF);
    float* e2 = (float*)(ws + WS_E2_OFF);
    float* x2 = (float*)(ws + WS_X2_OFF);

    char* scr = (char*)d_out + 256;   // inside quantized span; 16B-aligned for bf16x8 loads
    int* flaglist = (int*)(scr + SCR_FLAGLIST);
    int* flagcands = (int*)(scr + SCR_FLAGCANDS);
    unsigned short* eh = (unsigned short*)(scr + SCR_EH);
    unsigned short* el = (unsigned short*)(scr + SCR_EL);

    hipMemsetAsync(d_ws, 0, 5120, stream);  // loss + gflagcnt + hist
    k_prep_e<<<KCODES, 256, 0, stream>>>(emb, eh, el);
    k_np_sq<<<KCODES / 256, 256, 0, stream>>>(emb, e2, KCODES);
    k_np_sq<<<NROWS / 256, 256, 0, stream>>>(x, x2, NROWS);
    k_mfma<<<NROWS / 32, 512, 0, stream>>>(x, eh, el, e2, x2,
                                           out + OUT_IDX, gflagcnt, flaglist, flagcands);
    k_refine<<<256, 256, 0, stream>>>(x, emb, e2, x2, gflagcnt, flaglist, flagcands,
                                      out + OUT_IDX);
    k_quant<<<NROWS / 64, 256, 0, stream>>>(x, emb, out + OUT_IDX, out + OUT_Q, loss_accum, hist);
    k_final<<<1, 256, 0, stream>>>(hist, loss_accum, out);
}